// Round 7
// baseline (468.625 us; speedup 1.0000x reference)
//
#include <hip/hip_runtime.h>
#include <math.h>

// Problem constants
constexpr int kBS = 32, kM = 128, kNMAT = kBS * kM;         // 4096 (b,m) pairs
constexpr int kDIN = 64, kDOUT = 32, kMSZ = kDOUT * kDOUT;  // 1024 floats per 32x32
constexpr int kNSweep = 5;  // 4 sweeps -> absmax 0.0156 (1 quantum under threshold);
                            // 5 sweeps -> 0.0039 (4x margin). Keep 5.

// ws layout (floats):
//   P/log : [3][4096][1024]  (Q=0,K=1,V=2; overwritten in place by logs)
//   sumsq : [3][4096]        (||log||_F^2 per matrix)
//   attn  : [32][128][128]
// mean_log reuses the logQ region (dead after k_attn).
constexpr size_t OFF_SS   = (size_t)3 * kNMAT * kMSZ;
constexpr size_t OFF_ATTN = OFF_SS + (size_t)3 * kNMAT;

#define F4(p)  (*(float4*)(p))
#define CF4(p) (*(const float4*)(p))

// ---------------------------------------------------------------- bimap ----
// P_t = W_t^T X W_t for t in {Q,K,V}; one block per (b,m).
__global__ __launch_bounds__(256) void k_bimap(
    const float* __restrict__ x, const float* __restrict__ Wq,
    const float* __restrict__ Wk, const float* __restrict__ Wv,
    float* __restrict__ P) {
  __shared__ float Xs[64 * 68];   // X, row-major padded
  __shared__ float Wsh[64 * 32];  // current W, row-major
  __shared__ float Ts[64 * 36];   // T = X*W, padded
  const int t = threadIdx.x;
  const int bm = blockIdx.x;
  const float* xp = x + (size_t)bm * (kDIN * kDIN);
  {
    const int f0 = t * 16;
    const int r = f0 >> 6, c = f0 & 63;
    const float* src = xp + f0;
    float* dst = &Xs[r * 68 + c];
#pragma unroll
    for (int i = 0; i < 4; ++i) F4(dst + 4 * i) = CF4(src + 4 * i);
  }
  const int r0 = (t >> 3) * 2;   // stage-1 rows
  const int j0 = (t & 7) * 4;    // output cols
  const int i2 = t >> 3;         // stage-2 row
  for (int tt = 0; tt < 3; ++tt) {
    const float* W = (tt == 0) ? Wq : ((tt == 1) ? Wk : Wv);
    __syncthreads();  // protect Wsh/Ts from previous type (also covers Xs @ tt=0)
    F4(&Wsh[t * 8]) = CF4(W + t * 8);
    F4(&Wsh[t * 8 + 4]) = CF4(W + t * 8 + 4);
    __syncthreads();
    // stage 1: T = X * W   (64x32). X symmetric: X[r0][k] = Xs[k][r0] -> b64.
    float a0[4] = {0.f, 0.f, 0.f, 0.f}, a1[4] = {0.f, 0.f, 0.f, 0.f};
    for (int k = 0; k < 64; ++k) {
      const float2 x01 = *(const float2*)&Xs[k * 68 + r0];
      const float4 w = CF4(&Wsh[k * 32 + j0]);
      a0[0] += x01.x * w.x; a0[1] += x01.x * w.y; a0[2] += x01.x * w.z; a0[3] += x01.x * w.w;
      a1[0] += x01.y * w.x; a1[1] += x01.y * w.y; a1[2] += x01.y * w.z; a1[3] += x01.y * w.w;
    }
    F4(&Ts[r0 * 36 + j0])       = make_float4(a0[0], a0[1], a0[2], a0[3]);
    F4(&Ts[(r0 + 1) * 36 + j0]) = make_float4(a1[0], a1[1], a1[2], a1[3]);
    __syncthreads();
    // stage 2: P = W^T * T  (32x32)
    float b4[4] = {0.f, 0.f, 0.f, 0.f};
    for (int p = 0; p < 64; ++p) {
      const float wv = Wsh[p * 32 + i2];
      const float4 tv = CF4(&Ts[p * 36 + j0]);
      b4[0] += wv * tv.x; b4[1] += wv * tv.y; b4[2] += wv * tv.z; b4[3] += wv * tv.w;
    }
    F4(&P[((size_t)tt * kNMAT + bm) * kMSZ + i2 * 32 + j0]) =
        make_float4(b4[0], b4[1], b4[2], b4[3]);
  }
}

// ----------------------------------------------------- one-sided Jacobi ----
// Register-resident Brent-Luk one-sided Jacobi. Each wave processes FOUR
// matrices: two concurrent (lane-split: matrix = lane>>5) x two sequential.
// Grid 768 blocks = 3 blocks/CU (under the 4-block LDS cap) -> all waves
// resident, single dispatch pass, no tail (the R6 kernel's 1536 blocks at
// 4/CU cap ran 1.5 passes; the half-empty tail cost ~2x).
// Lane layout: g=lane&15 (pair group), sub=(lane>>4)&1 (row half).
// Ring exchange via update_dpp row_shl:1 / row_shr:1, bound_ctrl=off:
// out-of-range lanes keep `old`, which IS the tournament boundary value.
constexpr int kJSlot = 32 * 36 + 32;  // 1152 col data + 32 norms = 1184 floats
constexpr int kShl1 = 0x101, kShr1 = 0x111;

template <int CTRL>
__device__ __forceinline__ float updppf(float old_, float x) {
  return __builtin_bit_cast(float,
      __builtin_amdgcn_update_dpp(__builtin_bit_cast(int, old_),
                                  __builtin_bit_cast(int, x),
                                  CTRL, 0xf, 0xf, false));
}

__device__ __forceinline__ float xsign(float x, float s) {  // x * sgn(s)
  return __builtin_bit_cast(float,
      __builtin_bit_cast(int, x) ^
      (__builtin_bit_cast(int, s) & 0x80000000));
}

__global__ __launch_bounds__(256, 4) void k_jacobi_log(float* __restrict__ P,
                                                       float* __restrict__ sq) {
  __shared__ float lds[8 * kJSlot];  // 2 slots per wave (pair), reused per seq
  const int t = threadIdx.x;
  const int wid = t >> 6, lane = t & 63;
  const int g = lane & 15;           // pair group
  const int sub = (lane >> 4) & 1;   // row half
  const int off = sub * 16;
  const int mymat = lane >> 5;

  const bool is_g0 = (g == 0);
  // initial columns: g==0 -> {31, 0}; else {g, 31-g}
  const int p0 = is_g0 ? 31 : g;
  const int q0 = is_g0 ? 0 : 31 - g;

  for (int seq = 0; seq < 2; ++seq) {
    const size_t gbase = (size_t)blockIdx.x * 16 + wid * 4 + seq * 2;
    const size_t gid = gbase + mymat;
    float* A = P + gid * kMSZ;

    float cp[16], cq[16];
    {  // A is symmetric: column c == row c (row-major, 32 floats)
      const float* pr = A + p0 * 32 + off;
      const float* qr = A + q0 * 32 + off;
#pragma unroll
      for (int i = 0; i < 16; i += 4) {
        const float4 a = CF4(pr + i);
        cp[i] = a.x; cp[i + 1] = a.y; cp[i + 2] = a.z; cp[i + 3] = a.w;
        const float4 b = CF4(qr + i);
        cq[i] = b.x; cq[i + 1] = b.y; cq[i + 2] = b.z; cq[i + 3] = b.w;
      }
    }
    // initial squared norms (reduce across the 2 subs: lanes l, l^16)
    float app = 0.f, aqq = 0.f;
#pragma unroll
    for (int i = 0; i < 16; ++i) {
      app = fmaf(cp[i], cp[i], app);
      aqq = fmaf(cq[i], cq[i], aqq);
    }
    app += __shfl_xor(app, 16);
    aqq += __shfl_xor(aqq, 16);

    for (int sw = 0; sw < kNSweep; ++sw) {
      for (int r = 0; r < 31; ++r) {
        // apq = colp . colq (two FMA chains for ILP, then cross-sub reduce)
        float d0 = cp[0] * cq[0], d1 = cp[1] * cq[1];
#pragma unroll
        for (int i = 2; i < 16; i += 2) {
          d0 = fmaf(cp[i], cq[i], d0);
          d1 = fmaf(cp[i + 1], cq[i + 1], d1);
        }
        float apq = d0 + d1;
        apq += __shfl_xor(apq, 16);
        // rotation from (d, apq) with 3 transcendentals:
        //   h = sqrt(d^2 + 4 apq^2); t = sgn(d) * 2 apq / (|d| + h)
        //   c = rsq(1+t^2); s = t*c.   apq==0 -> t=0 -> exact identity.
        const float d = aqq - app;
        const float apq2 = 2.f * apq;
        float h2 = fmaf(d, d, apq2 * apq2);
        h2 = fmaxf(h2, 1e-38f);  // guard d=apq=0
        const float hr = __builtin_amdgcn_rsqf(h2);
        const float h = h2 * hr;
        const float den = fabsf(d) + h;
        const float t0 = apq2 * __builtin_amdgcn_rcpf(den);
        const float tt = xsign(t0, d);
        const float c = __builtin_amdgcn_rsqf(fmaf(tt, tt, 1.f));
        const float sn = tt * c;
        float np[16], nq[16];
#pragma unroll
        for (int i = 0; i < 16; ++i) {
          const float t1 = c * cp[i];
          const float t2 = sn * cp[i];
          np[i] = fmaf(-sn, cq[i], t1);
          nq[i] = fmaf(c, cq[i], t2);
        }
        // analytic norm update (rotation preserves app+aqq; np.nq == 0)
        const float c2 = c * c, s2 = sn * sn, cs2 = 2.f * c * sn;
        const float capp = fmaf(c2, app, fmaf(s2, aqq, -cs2 * apq));
        const float caqq = (app + aqq) - capp;
        // ring exchange
#pragma unroll
        for (int i = 0; i < 16; ++i) {
          const float cpm = updppf<kShl1>(nq[i], np[i]);
          cp[i] = is_g0 ? np[i] : cpm;
          cq[i] = updppf<kShr1>(cpm, nq[i]);
        }
        {
          const float capm = updppf<kShl1>(caqq, capp);
          app = is_g0 ? capp : capm;
          aqq = updppf<kShr1>(capm, caqq);
        }
      }
    }
    // write final columns to this matrix's LDS slot (column-major, stride 36)
    {
      float* Bs = lds + (wid * 2 + mymat) * kJSlot;
#pragma unroll
      for (int i = 0; i < 16; i += 4) {
        F4(&Bs[p0 * 36 + off + i]) = make_float4(cp[i], cp[i+1], cp[i+2], cp[i+3]);
        F4(&Bs[q0 * 36 + off + i]) = make_float4(cq[i], cq[i+1], cq[i+2], cq[i+3]);
      }
    }
    __builtin_amdgcn_wave_barrier();
    // two full-wave epilogue passes, one per matrix
#pragma unroll
    for (int m = 0; m < 2; ++m) {
      float* Bs = lds + (wid * 2 + m) * kJSlot;
      float* ncol = Bs + 1152;
      const size_t gm = gbase + m;
      float* Am = P + gm * kMSZ;
      {  // exact column norms -> sigma^2; w_c = log(sigma)/sigma^2; sumsq
        const int cc_ = lane & 31, h = lane >> 5;
        const float* col = &Bs[cc_ * 36 + h * 16];
        float ssum = 0.f;
#pragma unroll
        for (int i = 0; i < 16; i += 4) {
          const float4 v = CF4(col + i);
          ssum += v.x * v.x + v.y * v.y + v.z * v.z + v.w * v.w;
        }
        ssum += __shfl_xor(ssum, 32);
        const float lg = 0.5f * logf(ssum);  // log sigma_c
        float tot = lg * lg;
        tot += __shfl_xor(tot, 1);  tot += __shfl_xor(tot, 2);
        tot += __shfl_xor(tot, 4);  tot += __shfl_xor(tot, 8);
        tot += __shfl_xor(tot, 16); tot += __shfl_xor(tot, 32);
        if (lane == 0) sq[gm] = 0.5f * tot;  // each column counted twice
        if (h == 0) ncol[cc_] = lg / ssum;
      }
      __builtin_amdgcn_wave_barrier();
      {  // log A = B diag(w) B^T, 4x4 tile per lane, write back (row-major)
        const int rr = (lane >> 3) * 4, cc = (lane & 7) * 4;
        float acc[4][4] = {};
        for (int c = 0; c < 32; ++c) {
          const float w = ncol[c];
          const float4 br = CF4(&Bs[c * 36 + rr]);
          const float4 bc = CF4(&Bs[c * 36 + cc]);
          const float wr[4]  = {w * br.x, w * br.y, w * br.z, w * br.w};
          const float bcv[4] = {bc.x, bc.y, bc.z, bc.w};
#pragma unroll
          for (int i = 0; i < 4; ++i)
#pragma unroll
            for (int j2 = 0; j2 < 4; ++j2) acc[i][j2] += wr[i] * bcv[j2];
        }
#pragma unroll
        for (int i = 0; i < 4; ++i)
          F4(&Am[(rr + i) * 32 + cc]) =
              make_float4(acc[i][0], acc[i][1], acc[i][2], acc[i][3]);
      }
      __builtin_amdgcn_wave_barrier();
    }
  }
}

// ------------------------------------------------- scores/softmax/attn ----
// Block: (jt, b), 16-wide j tile -> 256 blocks (1/CU). K-chunk staged
// TRANSPOSED [k][i] so i-fragments are ds_read_b128; Q [k][j] -> b64.
__global__ __launch_bounds__(256) void k_attn(
    const float* __restrict__ P, const float* __restrict__ sq,
    float* __restrict__ attn) {
  __shared__ float Kt[32 * 132];   // [k][i], padded
  __shared__ float Qt[32 * 20];    // [k][j], padded
  __shared__ float Ss[128 * 20];   // scores [i][j]
  __shared__ float red[16 * 20];
  __shared__ float mcol[16];
  __shared__ float scol[16];
  const int t = threadIdx.x;
  const int b = blockIdx.y, jt = blockIdx.x;
  const int j0g = jt * 16;
  const float* logK = P + ((size_t)kNMAT + (size_t)b * kM) * kMSZ;
  const float* logQ = P + ((size_t)b * kM + j0g) * kMSZ;
  const int i0 = (t >> 3) * 4, j0 = (t & 7) * 2;
  float acc[4][2] = {};
  for (int dc = 0; dc < kMSZ; dc += 32) {
    __syncthreads();
    {  // stage Kt[k][i]: row r of logK, cols dc+c0..+15, transposed write
      const int r = t >> 1, c0 = (t & 1) * 16;
      const float* src = logK + (size_t)r * kMSZ + dc + c0;
#pragma unroll
      for (int ii = 0; ii < 16; ii += 4) {
        const float4 v = CF4(src + ii);
        Kt[(c0 + ii + 0) * 132 + r] = v.x;
        Kt[(c0 + ii + 1) * 132 + r] = v.y;
        Kt[(c0 + ii + 2) * 132 + r] = v.z;
        Kt[(c0 + ii + 3) * 132 + r] = v.w;
      }
    }
    {  // stage Qt[k][j]
      const int j = t >> 4, c0 = (t & 15) * 2;
      const float2 v = *(const float2*)(logQ + (size_t)j * kMSZ + dc + c0);
      Qt[(c0 + 0) * 20 + j] = v.x;
      Qt[(c0 + 1) * 20 + j] = v.y;
    }
    __syncthreads();
    for (int k = 0; k < 32; ++k) {
      const float4 kv = CF4(&Kt[k * 132 + i0]);
      const float2 qv = *(const float2*)&Qt[k * 20 + j0];
      acc[0][0] = fmaf(kv.x, qv.x, acc[0][0]);
      acc[0][1] = fmaf(kv.x, qv.y, acc[0][1]);
      acc[1][0] = fmaf(kv.y, qv.x, acc[1][0]);
      acc[1][1] = fmaf(kv.y, qv.y, acc[1][1]);
      acc[2][0] = fmaf(kv.z, qv.x, acc[2][0]);
      acc[2][1] = fmaf(kv.z, qv.y, acc[2][1]);
      acc[3][0] = fmaf(kv.w, qv.x, acc[3][0]);
      acc[3][1] = fmaf(kv.w, qv.y, acc[3][1]);
    }
  }
  {  // energy -> scores, into Ss[i][j]
    float k2v[4], q2v[2];
#pragma unroll
    for (int i = 0; i < 4; ++i) k2v[i] = sq[kNMAT + b * kM + i0 + i];
#pragma unroll
    for (int j2 = 0; j2 < 2; ++j2) q2v[j2] = sq[b * kM + j0g + j0 + j2];
#pragma unroll
    for (int i = 0; i < 4; ++i)
#pragma unroll
      for (int j2 = 0; j2 < 2; ++j2) {
        float e = k2v[i] + q2v[j2] - 2.f * acc[i][j2];
        e = fmaxf(e, 0.f);
        Ss[(i0 + i) * 20 + (j0 + j2)] = 1.f / (1.f + log1pf(e));
      }
  }
  __syncthreads();
  const int jl = t & 15, grp = t >> 4;  // 16 groups x 16 j-cols; group: 8 i-rows
  {
    float m = -1e30f;
#pragma unroll
    for (int i = 0; i < 8; ++i) m = fmaxf(m, Ss[(grp * 8 + i) * 20 + jl]);
    red[grp * 20 + jl] = m;
  }
  __syncthreads();
  if (t < 16) {
    float m = red[t];
#pragma unroll
    for (int g = 1; g < 16; ++g) m = fmaxf(m, red[g * 20 + t]);
    mcol[t] = m;
  }
  __syncthreads();
  {
    const float mj = mcol[jl];
    float s = 0.f;
#pragma unroll
    for (int i = 0; i < 8; ++i) s += expf(Ss[(grp * 8 + i) * 20 + jl] - mj);
    red[grp * 20 + jl] = s;
  }
  __syncthreads();
  if (t < 16) {
    float s = red[t];
#pragma unroll
    for (int g = 1; g < 16; ++g) s += red[g * 20 + t];
    scol[t] = 1.f / s;
  }
  __syncthreads();
  {  // write attn[b][j][i], coalesced in i
    const int il = t & 31, jg = t >> 5;
#pragma unroll
    for (int rep = 0; rep < 2; ++rep) {
      const int j2 = jg + rep * 8;
      const float mj = mcol[j2], is = scol[j2];
      float* dst = attn + ((size_t)b * kM + j0g + j2) * kM;
#pragma unroll
      for (int c4 = 0; c4 < 4; ++c4) {
        const int i = il + c4 * 32;
        dst[i] = expf(Ss[i * 20 + j2] - mj) * is;
      }
    }
  }
}

// -------------------------------------------------------------- meanlog ----
// ML[b][j][:] = sum_i attn[b][j][i] * logV[b][i][:]. Block: (jt, b), 16 j.
// All 16 j-accumulators in registers (thread owns 4 d-cols); attn weights
// broadcast from LDS (b128 per 4k); V streamed from global (L2-resident).
__global__ __launch_bounds__(256) void k_meanlog(
    const float* __restrict__ attn, const float* __restrict__ P,
    float* __restrict__ ML) {
  __shared__ float As[16 * 132];
  const int t = threadIdx.x;
  const int b = blockIdx.y, jt = blockIdx.x;
  const int j0g = jt * 16;
  const float* logV = P + ((size_t)2 * kNMAT + (size_t)b * kM) * kMSZ;
  {  // stage attn tile [16][128]
    const int j = t >> 4, k0 = (t & 15) * 8;
    const float* src = attn + ((size_t)b * kM + j0g + j) * kM + k0;
    F4(&As[j * 132 + k0])     = CF4(src);
    F4(&As[j * 132 + k0 + 4]) = CF4(src + 4);
  }
  __syncthreads();
  const int d0 = t * 4;
  float acc[16][4] = {};
  for (int k = 0; k < kM; k += 4) {
    float4 vr[4];
#pragma unroll
    for (int kk = 0; kk < 4; ++kk)
      vr[kk] = CF4(&logV[(size_t)(k + kk) * kMSZ + d0]);
#pragma unroll
    for (int j = 0; j < 16; ++j) {
      const float4 w = CF4(&As[j * 132 + k]);
      const float wv[4] = {w.x, w.y, w.z, w.w};
#pragma unroll
      for (int kk = 0; kk < 4; ++kk) {
        const float* vv = (const float*)&vr[kk];
#pragma unroll
        for (int dd = 0; dd < 4; ++dd)
          acc[j][dd] = fmaf(wv[kk], vv[dd], acc[j][dd]);
      }
    }
  }
#pragma unroll
  for (int j = 0; j < 16; ++j)
    F4(&ML[((size_t)b * kM + j0g + j) * kMSZ + d0]) =
        make_float4(acc[j][0], acc[j][1], acc[j][2], acc[j][3]);
}

// ------------------------------------------------------------------ exp ----
// out = exp(S): scaling-and-squaring + degree-7 Horner Taylor (||M||<=0.5
// after scaling -> truncation 1.6e-7, invisible vs the 0.0039 floor).
// 4 waves/block, one matrix per wave, private LDS slot, no s_barrier.
// M and T are SYMMETRIC, so row-fragments load as b128 from [k][r].
constexpr int kESlot = 2 * 1152;  // Mb + Tb

__global__ __launch_bounds__(256) void k_expm(const float* __restrict__ ML,
                                              float* __restrict__ out) {
  __shared__ float lds[4 * kESlot];
  const int t = threadIdx.x;
  const int wid = t >> 6, lane = t & 63;
  const size_t bm = (size_t)blockIdx.x * 4 + wid;
  float* Mb = lds + wid * kESlot;
  float* Tb = Mb + 1152;
  const float* S = ML + bm * kMSZ;
  const int r = lane >> 1, c0 = (lane & 1) * 16;
  float4 v0 = CF4(S + r * 32 + c0),     v1 = CF4(S + r * 32 + c0 + 4),
         v2 = CF4(S + r * 32 + c0 + 8), v3 = CF4(S + r * 32 + c0 + 12);
  float lsum = v0.x*v0.x + v0.y*v0.y + v0.z*v0.z + v0.w*v0.w
             + v1.x*v1.x + v1.y*v1.y + v1.z*v1.z + v1.w*v1.w
             + v2.x*v2.x + v2.y*v2.y + v2.z*v2.z + v2.w*v2.w
             + v3.x*v3.x + v3.y*v3.y + v3.z*v3.z + v3.w*v3.w;
#pragma unroll
  for (int d = 1; d < 64; d <<= 1) lsum += __shfl_xor(lsum, d);
  const float fn = sqrtf(lsum);     // Frobenius norm >= spectral norm
  int sc = 0;
  if (fn > 0.5f) sc = (int)ceilf(log2f(fn * 2.0f));
  const float scale = exp2f((float)(-sc));
  v0.x*=scale; v0.y*=scale; v0.z*=scale; v0.w*=scale;
  v1.x*=scale; v1.y*=scale; v1.z*=scale; v1.w*=scale;
  v2.x*=scale; v2.y*=scale; v2.z*=scale; v2.w*=scale;
  v3.x*=scale; v3.y*=scale; v3.z*=scale; v3.w*=scale;
  F4(&Mb[r * 36 + c0])      = v0;
  F4(&Mb[r * 36 + c0 + 4])  = v1;
  F4(&Mb[r * 36 + c0 + 8])  = v2;
  F4(&Mb[r * 36 + c0 + 12]) = v3;
  __builtin_amdgcn_wave_barrier();
  const int rr = (lane >> 3) * 4, cc = (lane & 7) * 4;
#pragma unroll
  for (int i = 0; i < 4; ++i) {  // T = I + M/7
    float4 v = F4(&Mb[(rr + i) * 36 + cc]);
    v.x = v.x * (1.f/7.f) + ((rr + i == cc + 0) ? 1.f : 0.f);
    v.y = v.y * (1.f/7.f) + ((rr + i == cc + 1) ? 1.f : 0.f);
    v.z = v.z * (1.f/7.f) + ((rr + i == cc + 2) ? 1.f : 0.f);
    v.w = v.w * (1.f/7.f) + ((rr + i == cc + 3) ? 1.f : 0.f);
    F4(&Tb[(rr + i) * 36 + cc]) = v;
  }
  __builtin_amdgcn_wave_barrier();
  for (int j = 6; j >= 1; --j) {  // T <- I + (M*T)/j, in place
    float a4[4][4] = {};
    for (int k = 0; k < 32; ++k) {
      const float4 mv = CF4(&Mb[k * 36 + rr]);  // M[rr..rr+3][k] by symmetry
      const float mvv[4] = {mv.x, mv.y, mv.z, mv.w};
      const float4 tv = CF4(&Tb[k * 36 + cc]);
      const float tvv[4] = {tv.x, tv.y, tv.z, tv.w};
#pragma unroll
      for (int i = 0; i < 4; ++i)
#pragma unroll
        for (int j2 = 0; j2 < 4; ++j2) a4[i][j2] += mvv[i] * tvv[j2];
    }
    const float inv = 1.f / (float)j;
#pragma unroll
    for (int i = 0; i < 4; ++i) {
      float4 v;
      v.x = a4[i][0] * inv + ((rr + i == cc + 0) ? 1.f : 0.f);
      v.y = a4[i][1] * inv + ((rr + i == cc + 1) ? 1.f : 0.f);
      v.z = a4[i][2] * inv + ((rr + i == cc + 2) ? 1.f : 0.f);
      v.w = a4[i][3] * inv + ((rr + i == cc + 3) ? 1.f : 0.f);
      F4(&Tb[(rr + i) * 36 + cc]) = v;
    }
    __builtin_amdgcn_wave_barrier();
  }
  for (int st = 0; st < sc; ++st) {  // T <- T*T, in place (T symmetric)
    float a4[4][4] = {};
    for (int k = 0; k < 32; ++k) {
      const float4 mv = CF4(&Tb[k * 36 + rr]);  // T[rr..rr+3][k] by symmetry
      const float mvv[4] = {mv.x, mv.y, mv.z, mv.w};
      const float4 tv = CF4(&Tb[k * 36 + cc]);
      const float tvv[4] = {tv.x, tv.y, tv.z, tv.w};
#pragma unroll
      for (int i = 0; i < 4; ++i)
#pragma unroll
        for (int j2 = 0; j2 < 4; ++j2) a4[i][j2] += mvv[i] * tvv[j2];
    }
#pragma unroll
    for (int i = 0; i < 4; ++i)
      F4(&Tb[(rr + i) * 36 + cc]) =
          make_float4(a4[i][0], a4[i][1], a4[i][2], a4[i][3]);
    __builtin_amdgcn_wave_barrier();
  }
#pragma unroll
  for (int i = 0; i < 4; ++i) {
    const float4 v = CF4(&Tb[(rr + i) * 36 + cc]);
    F4(&out[bm * kMSZ + (rr + i) * 32 + cc]) = v;
  }
}

// -------------------------------------------------------------- launch ----
extern "C" void kernel_launch(void* const* d_in, const int* in_sizes, int n_in,
                              void* d_out, int out_size, void* d_ws, size_t ws_size,
                              hipStream_t stream) {
  const float* x  = (const float*)d_in[0];
  const float* Wq = (const float*)d_in[1];
  const float* Wk = (const float*)d_in[2];
  const float* Wv = (const float*)d_in[3];
  float* ws   = (float*)d_ws;
  float* P    = ws;                 // [3][4096][1024]
  float* sq   = ws + OFF_SS;        // [3][4096]
  float* attn = ws + OFF_ATTN;      // [32][128][128]
  float* ML   = ws;                 // reuse logQ region (dead after k_attn)
  float* out  = (float*)d_out;

  k_bimap<<<kNMAT, 256, 0, stream>>>(x, Wq, Wk, Wv, P);
  k_jacobi_log<<<3 * kNMAT / 16, 256, 0, stream>>>(P, sq);
  k_attn<<<dim3(8, kBS), 256, 0, stream>>>(P, sq, attn);
  k_meanlog<<<dim3(8, kBS), 256, 0, stream>>>(attn, P, ML);
  k_expm<<<kNMAT / 4, 256, 0, stream>>>(ML, out);
}